// Round 7
// baseline (1286.080 us; speedup 1.0000x reference)
//
#include <hip/hip_runtime.h>

#define TT 2048
#define BB 64
#define HH 256   // EMB == HID == 256

typedef _Float16 half2_t __attribute__((ext_vector_type(2)));
typedef _Float16 half8_t __attribute__((ext_vector_type(8)));
typedef float f32x4 __attribute__((ext_vector_type(4)));
typedef int i32x4 __attribute__((ext_vector_type(4)));

static __device__ __forceinline__ float dot2i(int h, int w, float acc) {
  return __builtin_amdgcn_fdot2(__builtin_bit_cast(half2_t, h),
                                __builtin_bit_cast(half2_t, w), acc, false);
}

// ---------------------------------------------------------------------------
// prep: transpose + fp16-convert W_ih and W_hh into [N][K] row-major.
// ---------------------------------------------------------------------------
__global__ void prep_kernel(const float* __restrict__ Wih, const float* __restrict__ Whh,
                            _Float16* __restrict__ WihT, _Float16* __restrict__ WhhT) {
  const int n = blockIdx.x;   // output column
  const int k = threadIdx.x;  // input row
  WihT[n * HH + k] = (_Float16)Wih[k * HH + n];
  WhhT[n * HH + k] = (_Float16)Whh[k * HH + n];
}

// ---------------------------------------------------------------------------
// Part A: U[t][b][n] = (emb[source[b][t]] @ W_ih)[n] + b_ih[n] + b_hh[n], fp16.
// (unchanged — verified correct; scan dominates runtime)
// ---------------------------------------------------------------------------
__global__ __launch_bounds__(256, 2) void embed_gemm_kernel(
    const int* __restrict__ source, const float* __restrict__ emb,
    const _Float16* __restrict__ WihT, const float* __restrict__ b_ih,
    const float* __restrict__ b_hh, _Float16* __restrict__ U) {
  const int t = blockIdx.x;
  const int nbase = blockIdx.y * 64;
  __shared__ __align__(16) _Float16 Bs[64][280];

  const int tid = threadIdx.x;
  for (int c = tid; c < 64 * 32; c += 256) {
    const int n = c >> 5;
    const int ko = (c & 31) * 8;
    *(half8_t*)&Bs[n][ko] = *(const half8_t*)(WihT + (size_t)(nbase + n) * HH + ko);
  }
  __syncthreads();

  const int lane = tid & 63;
  const int wave = tid >> 6;
  const int row16 = lane & 15;
  const int quad = lane >> 4;
  const int b = wave * 16 + row16;              // A-fragment row = batch
  const int src = source[b * TT + t];           // source is [B][T]
  const float* arow = emb + (size_t)src * HH + quad * 8;

  f32x4 acc[4];
#pragma unroll
  for (int ct = 0; ct < 4; ++ct) acc[ct] = (f32x4){0.f, 0.f, 0.f, 0.f};

#pragma unroll
  for (int kt = 0; kt < 8; ++kt) {
    const float4 x0 = *(const float4*)(arow + kt * 32);
    const float4 x1 = *(const float4*)(arow + kt * 32 + 4);
    half8_t af;
    af[0] = (_Float16)x0.x; af[1] = (_Float16)x0.y;
    af[2] = (_Float16)x0.z; af[3] = (_Float16)x0.w;
    af[4] = (_Float16)x1.x; af[5] = (_Float16)x1.y;
    af[6] = (_Float16)x1.z; af[7] = (_Float16)x1.w;
#pragma unroll
    for (int ct = 0; ct < 4; ++ct) {
      const half8_t bf = *(const half8_t*)&Bs[ct * 16 + row16][quad * 8 + kt * 32];
      acc[ct] = __builtin_amdgcn_mfma_f32_16x16x32_f16(af, bf, acc[ct], 0, 0, 0);
    }
  }

#pragma unroll
  for (int ct = 0; ct < 4; ++ct) {
    const int nn = nbase + ct * 16 + row16;     // C col = lane&15
    const float bias = b_ih[nn] + b_hh[nn];
#pragma unroll
    for (int r = 0; r < 4; ++r) {
      const int bb = wave * 16 + quad * 4 + r;  // C row = quad*4 + reg
      U[((size_t)t * BB + bb) * HH + nn] = (_Float16)(acc[ct][r] + bias);
    }
  }
}

// ---------------------------------------------------------------------------
// Part B: recurrence — 512 thr + waves_per_eu(2,2) + batched/pinned h-reads.
//   R6 post-mortem: VGPR=132 = 128 weights + ~4 scratch — compiler JIT-read
//   hv chunk-by-chunk; at 1 wave/SIMD each of the 8 reads exposed ~120 cy of
//   LDS latency => ~1150 cy/step. Fix: (a) 2 waves/SIMD so a co-resident
//   wave's dots cover LDS latency; (b) one asm pin over ALL hv (and all wr)
//   registers — loads must complete before the single asm, so the 8 reads
//   issue back-to-back with ONE lgkmcnt wait, not 8 serialized round-trips.
//   Lane map (R5): wave w in [0,8) owns outputs [32w,32w+32); jo=l>>2,
//   kk=l&3; lane does outputs {32w+jo, 32w+jo+16} over k-quarter
//   [64kk,64kk+64) => wr = 16 i32x4 = 64 regs + hv 32 + misc ~ 110 < 256
//   budget at waves_per_eu(2,2). Bank-rotated chunks c=(i+2kk)&7 (disjoint
//   bank groups per kk). Quad-DPP kk-reduction; lanes kk<2 finalize.
// ---------------------------------------------------------------------------
__global__ __launch_bounds__(512)
__attribute__((amdgpu_waves_per_eu(2, 2)))
void rnn_scan_kernel(
    const _Float16* __restrict__ U, const _Float16* __restrict__ WhhT,
    float* __restrict__ out) {
  const int b = blockIdx.x;
  const int tid = threadIdx.x;
  const int w = tid >> 6;   // wave in [0,8)
  const int l = tid & 63;
  const int jo = l >> 2;    // [0,16)
  const int kk = l & 3;     // k-quarter

  __shared__ __align__(16) _Float16 hbuf[2][HH];  // 1 KB ping-pong

  // wr[m][i]: halfs [64kk + 8*((i+2kk)&7) .. +8) of W^T row 32w + jo + 16m
  i32x4 wr[2][8];
#pragma unroll
  for (int m = 0; m < 2; ++m) {
    const _Float16* base = WhhT + (size_t)(32 * w + jo + 16 * m) * HH + 64 * kk;
#pragma unroll
    for (int i = 0; i < 8; ++i) {
      const int c = (i + 2 * kk) & 7;
      wr[m][i] = *(const i32x4*)(base + 8 * c);
    }
  }
  // Single pin for all 16 weight quads: resident, not rematerializable.
  asm volatile("" : "+v"(wr[0][0]), "+v"(wr[0][1]), "+v"(wr[0][2]), "+v"(wr[0][3]),
                    "+v"(wr[0][4]), "+v"(wr[0][5]), "+v"(wr[0][6]), "+v"(wr[0][7]),
                    "+v"(wr[1][0]), "+v"(wr[1][1]), "+v"(wr[1][2]), "+v"(wr[1][3]),
                    "+v"(wr[1][4]), "+v"(wr[1][5]), "+v"(wr[1][6]), "+v"(wr[1][7]));

  if (tid < HH) hbuf[0][tid] = (_Float16)0.f;  // h0 = 0

  const int jstar = 32 * w + jo + 16 * (kk & 1);  // lanes kk<2 finalize
  const _Float16* Up = U + b * HH + jstar;
  _Float16 uA = Up[0];
  _Float16 uB = Up[(size_t)BB * HH];
  float hn = 0.f;
  __syncthreads();

  for (int t = 0; t < TT; ++t) {
    // ---- h-quarter reads: 8 b128, bank-rotated, batched + pinned ----
    const i32x4* hq = (const i32x4*)(hbuf[t & 1] + 64 * kk);
    i32x4 hv[8];
#pragma unroll
    for (int i = 0; i < 8; ++i) hv[i] = hq[(i + 2 * kk) & 7];
    // One asm over all 8: all reads issue first, ONE lgkmcnt wait.
    asm volatile("" : "+v"(hv[0]), "+v"(hv[1]), "+v"(hv[2]), "+v"(hv[3]),
                      "+v"(hv[4]), "+v"(hv[5]), "+v"(hv[6]), "+v"(hv[7]));

    // ---- partial dots: 2 outputs x 64 MACs = 64 fdot2, 2 indep chains ----
    float pa[2] = {0.f, 0.f};
#pragma unroll
    for (int i = 0; i < 8; ++i) {
      const i32x4 h4 = hv[i];
#pragma unroll
      for (int m = 0; m < 2; ++m) {
        const i32x4 w4 = wr[m][i];
        pa[m] = dot2i(h4[0], w4[0], pa[m]);
        pa[m] = dot2i(h4[1], w4[1], pa[m]);
        pa[m] = dot2i(h4[2], w4[2], pa[m]);
        pa[m] = dot2i(h4[3], w4[3], pa[m]);
      }
    }

    // ---- reduce over kk (quad lanes) via DPP quad_perm ----
#pragma unroll
    for (int m = 0; m < 2; ++m) {
      int x = __float_as_int(pa[m]);
      pa[m] += __int_as_float(__builtin_amdgcn_mov_dpp(x, 0xB1, 0xF, 0xF, true));  // xor1
      x = __float_as_int(pa[m]);
      pa[m] += __int_as_float(__builtin_amdgcn_mov_dpp(x, 0x4E, 0xF, 0xF, true));  // xor2
    }
    const float sum = (kk & 1) ? pa[1] : pa[0];

    const float a = (float)uA + sum;
    // tanh(a) = 1 - 2/(exp(2a)+1)
    const float e = __builtin_amdgcn_exp2f(a * 2.885390081777927f);  // 2*log2(e)
    hn = 1.f - 2.f * __builtin_amdgcn_rcpf(e + 1.f);
    if (kk < 2) hbuf[(t + 1) & 1][jstar] = (_Float16)hn;

    // u prefetch, 2 steps ahead (vmcnt off the critical path)
    uA = uB;
    uB = Up[(size_t)((t + 2) & (TT - 1)) * (BB * HH)];

    __syncthreads();  // the single per-step barrier
  }
  if (kk < 2) out[(size_t)b * HH + jstar] = hn;
}

// ---------------------------------------------------------------------------
extern "C" void kernel_launch(void* const* d_in, const int* in_sizes, int n_in,
                              void* d_out, int out_size, void* d_ws, size_t ws_size,
                              hipStream_t stream) {
  const int*   source = (const int*)d_in[0];
  const float* emb    = (const float*)d_in[1];
  const float* Wih    = (const float*)d_in[2];
  const float* Whh    = (const float*)d_in[3];
  const float* bih    = (const float*)d_in[4];
  const float* bhh    = (const float*)d_in[5];
  float* out = (float*)d_out;

  char* ws = (char*)d_ws;
  _Float16* U    = (_Float16*)ws;                    // 2048*64*256*2 = 67,108,864 B
  _Float16* WihT = (_Float16*)(ws + 67108864);       // 131,072 B
  _Float16* WhhT = (_Float16*)(ws + 67239936);       // 131,072 B (total ~67.4 MB)

  prep_kernel<<<dim3(256), dim3(256), 0, stream>>>(Wih, Whh, WihT, WhhT);
  embed_gemm_kernel<<<dim3(TT, 4), dim3(256), 0, stream>>>(source, emb, WihT, bih, bhh, U);
  rnn_scan_kernel<<<dim3(BB), dim3(512), 0, stream>>>(U, WhhT, out);
}

// Round 8
// 1048.844 us; speedup vs baseline: 1.2262x; 1.2262x over previous
//
#include <hip/hip_runtime.h>

#define TT 2048
#define BB 64
#define HH 256   // EMB == HID == 256

typedef _Float16 half2_t __attribute__((ext_vector_type(2)));
typedef _Float16 half8_t __attribute__((ext_vector_type(8)));
typedef float f32x4 __attribute__((ext_vector_type(4)));
typedef int i32x4 __attribute__((ext_vector_type(4)));

static __device__ __forceinline__ float dot2i(int h, int w, float acc) {
  return __builtin_amdgcn_fdot2(__builtin_bit_cast(half2_t, h),
                                __builtin_bit_cast(half2_t, w), acc, false);
}

// ---------------------------------------------------------------------------
// prep: transpose + fp16-convert W_ih and W_hh into [N][K] row-major.
// ---------------------------------------------------------------------------
__global__ void prep_kernel(const float* __restrict__ Wih, const float* __restrict__ Whh,
                            _Float16* __restrict__ WihT, _Float16* __restrict__ WhhT) {
  const int n = blockIdx.x;   // output column
  const int k = threadIdx.x;  // input row
  WihT[n * HH + k] = (_Float16)Wih[k * HH + n];
  WhhT[n * HH + k] = (_Float16)Whh[k * HH + n];
}

// ---------------------------------------------------------------------------
// Part A: U[t][b][n] = (emb[source[b][t]] @ W_ih)[n] + b_ih[n] + b_hh[n], fp16.
// (unchanged — verified correct; scan dominates runtime)
// ---------------------------------------------------------------------------
__global__ __launch_bounds__(256, 2) void embed_gemm_kernel(
    const int* __restrict__ source, const float* __restrict__ emb,
    const _Float16* __restrict__ WihT, const float* __restrict__ b_ih,
    const float* __restrict__ b_hh, _Float16* __restrict__ U) {
  const int t = blockIdx.x;
  const int nbase = blockIdx.y * 64;
  __shared__ __align__(16) _Float16 Bs[64][280];

  const int tid = threadIdx.x;
  for (int c = tid; c < 64 * 32; c += 256) {
    const int n = c >> 5;
    const int ko = (c & 31) * 8;
    *(half8_t*)&Bs[n][ko] = *(const half8_t*)(WihT + (size_t)(nbase + n) * HH + ko);
  }
  __syncthreads();

  const int lane = tid & 63;
  const int wave = tid >> 6;
  const int row16 = lane & 15;
  const int quad = lane >> 4;
  const int b = wave * 16 + row16;              // A-fragment row = batch
  const int src = source[b * TT + t];           // source is [B][T]
  const float* arow = emb + (size_t)src * HH + quad * 8;

  f32x4 acc[4];
#pragma unroll
  for (int ct = 0; ct < 4; ++ct) acc[ct] = (f32x4){0.f, 0.f, 0.f, 0.f};

#pragma unroll
  for (int kt = 0; kt < 8; ++kt) {
    const float4 x0 = *(const float4*)(arow + kt * 32);
    const float4 x1 = *(const float4*)(arow + kt * 32 + 4);
    half8_t af;
    af[0] = (_Float16)x0.x; af[1] = (_Float16)x0.y;
    af[2] = (_Float16)x0.z; af[3] = (_Float16)x0.w;
    af[4] = (_Float16)x1.x; af[5] = (_Float16)x1.y;
    af[6] = (_Float16)x1.z; af[7] = (_Float16)x1.w;
#pragma unroll
    for (int ct = 0; ct < 4; ++ct) {
      const half8_t bf = *(const half8_t*)&Bs[ct * 16 + row16][quad * 8 + kt * 32];
      acc[ct] = __builtin_amdgcn_mfma_f32_16x16x32_f16(af, bf, acc[ct], 0, 0, 0);
    }
  }

#pragma unroll
  for (int ct = 0; ct < 4; ++ct) {
    const int nn = nbase + ct * 16 + row16;     // C col = lane&15
    const float bias = b_ih[nn] + b_hh[nn];
#pragma unroll
    for (int r = 0; r < 4; ++r) {
      const int bb = wave * 16 + quad * 4 + r;  // C row = quad*4 + reg
      U[((size_t)t * BB + bb) * HH + nn] = (_Float16)(acc[ct][r] + bias);
    }
  }
}

// ---------------------------------------------------------------------------
// Part B: recurrence. R6 config (weights resident at waves_per_eu(1,1),
// VGPR=132 proven) + two critical-path fixes:
//  (A) __syncthreads emits s_waitcnt vmcnt(0): a per-step global u-load gets
//      DRAINED AT EVERY BARRIER (~300-600 cy L2/L3 latency on the critical
//      path each step — the invariant term behind the R1-R7 ~1100-1380
//      cy/step plateau). Fix: 8-step unroll; issue all 8 next-chunk u-loads
//      at the chunk boundary; only the first barrier after issue drains
//      them (in flight ~1 full step) -> amortized ~0-30 cy/step.
//  (B) hv reads batched: 8 ds_read_b128 then ONE asm pin over all 8 ->
//      single lgkmcnt wait (~120 cy once) vs R6's 8 serialized round-trips.
// ---------------------------------------------------------------------------
__global__ __launch_bounds__(256)
__attribute__((amdgpu_waves_per_eu(1, 1)))
void rnn_scan_kernel(
    const _Float16* __restrict__ U, const _Float16* __restrict__ WhhT,
    float* __restrict__ out) {
  const int b = blockIdx.x;
  const int tid = threadIdx.x;
  const int w = tid >> 6;
  const int l = tid & 63;
  const int jj = l >> 2;
  const int kk = l & 3;

  __shared__ __align__(16) _Float16 hbuf[2][HH];  // 1 KB ping-pong

  // wr[m][i]: halfs [64kk + 8*((i+2kk)&7) .. +8) of W^T row 64w+jj+16m
  i32x4 wr[4][8];
#pragma unroll
  for (int m = 0; m < 4; ++m) {
    const _Float16* base = WhhT + (size_t)(64 * w + jj + 16 * m) * HH + 64 * kk;
#pragma unroll
    for (int i = 0; i < 8; ++i) {
      const int c = (i + 2 * kk) & 7;
      wr[m][i] = *(const i32x4*)(base + 8 * c);
    }
  }
  // Pin all 32 weight quads (two asms of 16 operands each).
  asm volatile("" : "+v"(wr[0][0]), "+v"(wr[0][1]), "+v"(wr[0][2]), "+v"(wr[0][3]),
                    "+v"(wr[0][4]), "+v"(wr[0][5]), "+v"(wr[0][6]), "+v"(wr[0][7]),
                    "+v"(wr[1][0]), "+v"(wr[1][1]), "+v"(wr[1][2]), "+v"(wr[1][3]),
                    "+v"(wr[1][4]), "+v"(wr[1][5]), "+v"(wr[1][6]), "+v"(wr[1][7]));
  asm volatile("" : "+v"(wr[2][0]), "+v"(wr[2][1]), "+v"(wr[2][2]), "+v"(wr[2][3]),
                    "+v"(wr[2][4]), "+v"(wr[2][5]), "+v"(wr[2][6]), "+v"(wr[2][7]),
                    "+v"(wr[3][0]), "+v"(wr[3][1]), "+v"(wr[3][2]), "+v"(wr[3][3]),
                    "+v"(wr[3][4]), "+v"(wr[3][5]), "+v"(wr[3][6]), "+v"(wr[3][7]));

  hbuf[0][tid] = (_Float16)0.f;  // h0 = 0

  const int jstar = 64 * w + jj + 16 * kk;  // output this lane finalizes
  const _Float16* Up = U + b * HH + jstar;  // step stride = BB*HH halfs

  // u chunk 0 (steps 0..7), resident in 8 static regs
  _Float16 uc[8], un[8];
#pragma unroll
  for (int s = 0; s < 8; ++s) uc[s] = Up[(size_t)s * (BB * HH)];

  float hn = 0.f;
  __syncthreads();

  for (int tc = 0; tc < TT; tc += 8) {
    // Issue ALL next-chunk u-loads now; consumed 8 steps later. Only the
    // first barrier below drains them (after ~1 step in flight).
    const int tn = (tc + 8) & (TT - 1);  // wraps harmlessly on last chunk
#pragma unroll
    for (int s = 0; s < 8; ++s) un[s] = Up[(size_t)(tn + s) * (BB * HH)];

#pragma unroll
    for (int s = 0; s < 8; ++s) {
      const int t = tc + s;
      // ---- h-quarter reads: 8 b128, bank-rotated, batched + pinned ----
      const i32x4* hq = (const i32x4*)(hbuf[t & 1] + 64 * kk);
      i32x4 hv[8];
#pragma unroll
      for (int i = 0; i < 8; ++i) hv[i] = hq[(i + 2 * kk) & 7];
      // One asm over all 8: reads issue back-to-back, ONE lgkmcnt wait.
      asm volatile("" : "+v"(hv[0]), "+v"(hv[1]), "+v"(hv[2]), "+v"(hv[3]),
                        "+v"(hv[4]), "+v"(hv[5]), "+v"(hv[6]), "+v"(hv[7]));

      // ---- partial dots: 4 outputs x 64 MACs = 128 fdot2, 4 chains ----
      float pa[4] = {0.f, 0.f, 0.f, 0.f};
#pragma unroll
      for (int i = 0; i < 8; ++i) {
        const i32x4 h4 = hv[i];
#pragma unroll
        for (int m = 0; m < 4; ++m) {
          const i32x4 w4 = wr[m][i];
          pa[m] = dot2i(h4[0], w4[0], pa[m]);
          pa[m] = dot2i(h4[1], w4[1], pa[m]);
          pa[m] = dot2i(h4[2], w4[2], pa[m]);
          pa[m] = dot2i(h4[3], w4[3], pa[m]);
        }
      }

      // ---- reduce over kk (quad lanes) via DPP quad_perm ----
#pragma unroll
      for (int m = 0; m < 4; ++m) {
        int x = __float_as_int(pa[m]);
        pa[m] += __int_as_float(__builtin_amdgcn_mov_dpp(x, 0xB1, 0xF, 0xF, true));  // xor1
        x = __float_as_int(pa[m]);
        pa[m] += __int_as_float(__builtin_amdgcn_mov_dpp(x, 0x4E, 0xF, 0xF, true));  // xor2
      }
      const float sum = (kk & 1) ? ((kk & 2) ? pa[3] : pa[1])
                                 : ((kk & 2) ? pa[2] : pa[0]);

      const float a = (float)uc[s] + sum;
      // tanh(a) = 1 - 2/(exp(2a)+1)
      const float e = __builtin_amdgcn_exp2f(a * 2.885390081777927f);  // 2*log2(e)
      hn = 1.f - 2.f * __builtin_amdgcn_rcpf(e + 1.f);
      hbuf[(t + 1) & 1][jstar] = (_Float16)hn;

      __syncthreads();  // single per-step barrier
    }

    // rotate chunks (8 v_movs per 8 steps; vmcnt wait lands here at worst)
#pragma unroll
    for (int s = 0; s < 8; ++s) uc[s] = un[s];
  }
  out[(size_t)b * HH + jstar] = hn;
}

// ---------------------------------------------------------------------------
extern "C" void kernel_launch(void* const* d_in, const int* in_sizes, int n_in,
                              void* d_out, int out_size, void* d_ws, size_t ws_size,
                              hipStream_t stream) {
  const int*   source = (const int*)d_in[0];
  const float* emb    = (const float*)d_in[1];
  const float* Wih    = (const float*)d_in[2];
  const float* Whh    = (const float*)d_in[3];
  const float* bih    = (const float*)d_in[4];
  const float* bhh    = (const float*)d_in[5];
  float* out = (float*)d_out;

  char* ws = (char*)d_ws;
  _Float16* U    = (_Float16*)ws;                    // 2048*64*256*2 = 67,108,864 B
  _Float16* WihT = (_Float16*)(ws + 67108864);       // 131,072 B
  _Float16* WhhT = (_Float16*)(ws + 67239936);       // 131,072 B (total ~67.4 MB)

  prep_kernel<<<dim3(256), dim3(256), 0, stream>>>(Wih, Whh, WihT, WhhT);
  embed_gemm_kernel<<<dim3(TT, 4), dim3(256), 0, stream>>>(source, emb, WihT, bih, bhh, U);
  rnn_scan_kernel<<<dim3(BB), dim3(256), 0, stream>>>(U, WhhT, out);
}

// Round 9
// 961.826 us; speedup vs baseline: 1.3371x; 1.0905x over previous
//
#include <hip/hip_runtime.h>

#define TT 2048
#define BB 64
#define HH 256   // EMB == HID == 256

typedef _Float16 half2_t __attribute__((ext_vector_type(2)));
typedef _Float16 half8_t __attribute__((ext_vector_type(8)));
typedef float f32x4 __attribute__((ext_vector_type(4)));
typedef int i32x4 __attribute__((ext_vector_type(4)));

// ---------------------------------------------------------------------------
// prep: transpose + fp16-convert W_ih and W_hh into [N][K] row-major.
// ---------------------------------------------------------------------------
__global__ void prep_kernel(const float* __restrict__ Wih, const float* __restrict__ Whh,
                            _Float16* __restrict__ WihT, _Float16* __restrict__ WhhT) {
  const int n = blockIdx.x;   // output column
  const int k = threadIdx.x;  // input row
  WihT[n * HH + k] = (_Float16)Wih[k * HH + n];
  WhhT[n * HH + k] = (_Float16)Whh[k * HH + n];
}

// ---------------------------------------------------------------------------
// Part A: U[t][b][n] = (emb[source[b][t]] @ W_ih)[n] + b_ih[n] + b_hh[n], fp16.
// (unchanged — verified correct; scan dominates runtime)
// ---------------------------------------------------------------------------
__global__ __launch_bounds__(256, 2) void embed_gemm_kernel(
    const int* __restrict__ source, const float* __restrict__ emb,
    const _Float16* __restrict__ WihT, const float* __restrict__ b_ih,
    const float* __restrict__ b_hh, _Float16* __restrict__ U) {
  const int t = blockIdx.x;
  const int nbase = blockIdx.y * 64;
  __shared__ __align__(16) _Float16 Bs[64][280];

  const int tid = threadIdx.x;
  for (int c = tid; c < 64 * 32; c += 256) {
    const int n = c >> 5;
    const int ko = (c & 31) * 8;
    *(half8_t*)&Bs[n][ko] = *(const half8_t*)(WihT + (size_t)(nbase + n) * HH + ko);
  }
  __syncthreads();

  const int lane = tid & 63;
  const int wave = tid >> 6;
  const int row16 = lane & 15;
  const int quad = lane >> 4;
  const int b = wave * 16 + row16;              // A-fragment row = batch
  const int src = source[b * TT + t];           // source is [B][T]
  const float* arow = emb + (size_t)src * HH + quad * 8;

  f32x4 acc[4];
#pragma unroll
  for (int ct = 0; ct < 4; ++ct) acc[ct] = (f32x4){0.f, 0.f, 0.f, 0.f};

#pragma unroll
  for (int kt = 0; kt < 8; ++kt) {
    const float4 x0 = *(const float4*)(arow + kt * 32);
    const float4 x1 = *(const float4*)(arow + kt * 32 + 4);
    half8_t af;
    af[0] = (_Float16)x0.x; af[1] = (_Float16)x0.y;
    af[2] = (_Float16)x0.z; af[3] = (_Float16)x0.w;
    af[4] = (_Float16)x1.x; af[5] = (_Float16)x1.y;
    af[6] = (_Float16)x1.z; af[7] = (_Float16)x1.w;
#pragma unroll
    for (int ct = 0; ct < 4; ++ct) {
      const half8_t bf = *(const half8_t*)&Bs[ct * 16 + row16][quad * 8 + kt * 32];
      acc[ct] = __builtin_amdgcn_mfma_f32_16x16x32_f16(af, bf, acc[ct], 0, 0, 0);
    }
  }

#pragma unroll
  for (int ct = 0; ct < 4; ++ct) {
    const int nn = nbase + ct * 16 + row16;     // C col = lane&15
    const float bias = b_ih[nn] + b_hh[nn];
#pragma unroll
    for (int r = 0; r < 4; ++r) {
      const int bb = wave * 16 + quad * 4 + r;  // C row = quad*4 + reg
      U[((size_t)t * BB + bb) * HH + nn] = (_Float16)(acc[ct][r] + bias);
    }
  }
}

// ---------------------------------------------------------------------------
// Part B: recurrence via MFMA with M-broadcast.
//   R8 post-mortem: fdot2 needs BOTH operands in arch VGPRs; 128 weight regs
//   + working set exceed what the allocator grants arch-side, so h fragments
//   shuttled through AGPRs every step (~256 cy/step VALU excess). MFMA reads
//   its operands from VGPR *or* AGPR natively — the shuttle vanishes and the
//   idle half of the unified file finally does work.
//   Trick: A[m][k] = h[32c+k] for ALL m (broadcast fragment) => every C row
//   equals y = Whh^T · h. No M-waste correctness cost; 8 broadcast b128
//   h-reads/step as before.
//   Wave w owns n in [64w,64w+64): 4 C-tiles (tt) x 8 k-chunks (c) = 32
//   MFMAs/step in 4 interleaved k-accumulation chains. wb[tt][c] = B-frag
//   (n=lane&15, k=quad*8+j — same proven layout as embed_gemm).
//   Finalize: quad q takes tile tt=q => thread tid owns output n = tid
//   (3 cndmasks); + u, tanh, one b16 write to ping-pong hbuf; 1 barrier/step.
//   u prefetched in 8-step chunks (R8 mechanism, keeps vmcnt off the path).
// ---------------------------------------------------------------------------
__global__ __launch_bounds__(256)
__attribute__((amdgpu_waves_per_eu(1, 1)))
void rnn_scan_kernel(
    const _Float16* __restrict__ U, const _Float16* __restrict__ WhhT,
    float* __restrict__ out) {
  const int b = blockIdx.x;
  const int tid = threadIdx.x;
  const int w = tid >> 6;
  const int l = tid & 63;
  const int col = l & 15;    // n within tile
  const int quad = l >> 4;   // MFMA quad / finalize tile

  __shared__ __align__(16) _Float16 hbuf[2][HH];  // 1 KB ping-pong

  // wb[tt][c]: B-frag for n-tile 64w+16tt, k-chunk c.
  // Lane reads WhhT[(64w+16tt+col)][32c + quad*8 .. +8] (16B aligned).
  half8_t wb[4][8];
#pragma unroll
  for (int tt = 0; tt < 4; ++tt) {
    const _Float16* base = WhhT + (size_t)(64 * w + 16 * tt + col) * HH + quad * 8;
#pragma unroll
    for (int c = 0; c < 8; ++c) wb[tt][c] = *(const half8_t*)(base + 32 * c);
  }
  // Pin so the one-time loads can't be sunk into the loop (R4 lesson).
  asm volatile("" : "+v"(wb[0][0]), "+v"(wb[0][1]), "+v"(wb[0][2]), "+v"(wb[0][3]),
                    "+v"(wb[0][4]), "+v"(wb[0][5]), "+v"(wb[0][6]), "+v"(wb[0][7]),
                    "+v"(wb[1][0]), "+v"(wb[1][1]), "+v"(wb[1][2]), "+v"(wb[1][3]),
                    "+v"(wb[1][4]), "+v"(wb[1][5]), "+v"(wb[1][6]), "+v"(wb[1][7]));
  asm volatile("" : "+v"(wb[2][0]), "+v"(wb[2][1]), "+v"(wb[2][2]), "+v"(wb[2][3]),
                    "+v"(wb[2][4]), "+v"(wb[2][5]), "+v"(wb[2][6]), "+v"(wb[2][7]),
                    "+v"(wb[3][0]), "+v"(wb[3][1]), "+v"(wb[3][2]), "+v"(wb[3][3]),
                    "+v"(wb[3][4]), "+v"(wb[3][5]), "+v"(wb[3][6]), "+v"(wb[3][7]));

  hbuf[0][tid] = (_Float16)0.f;  // h0 = 0

  // Thread tid finalizes output n = tid: u stream is per-thread contiguous.
  const _Float16* Up = U + b * HH + tid;  // step stride = BB*HH halfs
  _Float16 uc[8], un[8];
#pragma unroll
  for (int s = 0; s < 8; ++s) uc[s] = Up[(size_t)s * (BB * HH)];

  float hn = 0.f;
  __syncthreads();

  for (int tc = 0; tc < TT; tc += 8) {
    // Issue all next-chunk u-loads; only the first barrier after drains them.
    const int tn = (tc + 8) & (TT - 1);
#pragma unroll
    for (int s = 0; s < 8; ++s) un[s] = Up[(size_t)(tn + s) * (BB * HH)];

#pragma unroll
    for (int s = 0; s < 8; ++s) {
      const int t = tc + s;

      // ---- A-frags: broadcast h chunks; all lanes of a quad read same 16B ----
      const _Float16* hrow = hbuf[t & 1] + quad * 8;
      half8_t ha[8];
#pragma unroll
      for (int c = 0; c < 8; ++c) ha[c] = *(const half8_t*)(hrow + 32 * c);

      // ---- 32 MFMAs: 4 independent k-chains (one per n-tile) ----
      f32x4 cacc[4];
#pragma unroll
      for (int tt = 0; tt < 4; ++tt) cacc[tt] = (f32x4){0.f, 0.f, 0.f, 0.f};
#pragma unroll
      for (int c = 0; c < 8; ++c)
#pragma unroll
        for (int tt = 0; tt < 4; ++tt)
          cacc[tt] = __builtin_amdgcn_mfma_f32_16x16x32_f16(ha[c], wb[tt][c], cacc[tt], 0, 0, 0);

      // ---- finalize: quad q owns tile q  =>  n = 64w + 16q + col = tid ----
      // (all C rows are identical by construction; reg 0 suffices)
      float y = cacc[0][0];
      y = (quad == 1) ? cacc[1][0] : y;
      y = (quad == 2) ? cacc[2][0] : y;
      y = (quad == 3) ? cacc[3][0] : y;

      const float a = (float)uc[s] + y;
      // tanh(a) = 1 - 2/(exp(2a)+1)
      const float e = __builtin_amdgcn_exp2f(a * 2.885390081777927f);  // 2*log2(e)
      hn = 1.f - 2.f * __builtin_amdgcn_rcpf(e + 1.f);
      hbuf[(t + 1) & 1][tid] = (_Float16)hn;

      __syncthreads();  // single per-step barrier
    }
#pragma unroll
    for (int s = 0; s < 8; ++s) uc[s] = un[s];
  }
  out[(size_t)b * HH + tid] = hn;
}

// ---------------------------------------------------------------------------
extern "C" void kernel_launch(void* const* d_in, const int* in_sizes, int n_in,
                              void* d_out, int out_size, void* d_ws, size_t ws_size,
                              hipStream_t stream) {
  const int*   source = (const int*)d_in[0];
  const float* emb    = (const float*)d_in[1];
  const float* Wih    = (const float*)d_in[2];
  const float* Whh    = (const float*)d_in[3];
  const float* bih    = (const float*)d_in[4];
  const float* bhh    = (const float*)d_in[5];
  float* out = (float*)d_out;

  char* ws = (char*)d_ws;
  _Float16* U    = (_Float16*)ws;                    // 2048*64*256*2 = 67,108,864 B
  _Float16* WihT = (_Float16*)(ws + 67108864);       // 131,072 B
  _Float16* WhhT = (_Float16*)(ws + 67239936);       // 131,072 B (total ~67.4 MB)

  prep_kernel<<<dim3(256), dim3(256), 0, stream>>>(Wih, Whh, WihT, WhhT);
  embed_gemm_kernel<<<dim3(TT, 4), dim3(256), 0, stream>>>(source, emb, WihT, bih, bhh, U);
  rnn_scan_kernel<<<dim3(BB), dim3(256), 0, stream>>>(U, WhhT, out);
}

// Round 10
// 946.214 us; speedup vs baseline: 1.3592x; 1.0165x over previous
//
#include <hip/hip_runtime.h>

#define TT 2048
#define BB 64
#define HH 256   // EMB == HID == 256

typedef _Float16 half2_t __attribute__((ext_vector_type(2)));
typedef _Float16 half8_t __attribute__((ext_vector_type(8)));
typedef float f32x4 __attribute__((ext_vector_type(4)));
typedef int i32x4 __attribute__((ext_vector_type(4)));

// ---------------------------------------------------------------------------
// prep: transpose + fp16-convert W_ih and W_hh into [N][K] row-major.
// ---------------------------------------------------------------------------
__global__ void prep_kernel(const float* __restrict__ Wih, const float* __restrict__ Whh,
                            _Float16* __restrict__ WihT, _Float16* __restrict__ WhhT) {
  const int n = blockIdx.x;   // output column
  const int k = threadIdx.x;  // input row
  WihT[n * HH + k] = (_Float16)Wih[k * HH + n];
  WhhT[n * HH + k] = (_Float16)Whh[k * HH + n];
}

// ---------------------------------------------------------------------------
// Part A: U[t][b][n] = (emb[source[b][t]] @ W_ih)[n] + b_ih[n] + b_hh[n], fp16.
// (unchanged — verified correct; scan dominates runtime)
// ---------------------------------------------------------------------------
__global__ __launch_bounds__(256, 2) void embed_gemm_kernel(
    const int* __restrict__ source, const float* __restrict__ emb,
    const _Float16* __restrict__ WihT, const float* __restrict__ b_ih,
    const float* __restrict__ b_hh, _Float16* __restrict__ U) {
  const int t = blockIdx.x;
  const int nbase = blockIdx.y * 64;
  __shared__ __align__(16) _Float16 Bs[64][280];

  const int tid = threadIdx.x;
  for (int c = tid; c < 64 * 32; c += 256) {
    const int n = c >> 5;
    const int ko = (c & 31) * 8;
    *(half8_t*)&Bs[n][ko] = *(const half8_t*)(WihT + (size_t)(nbase + n) * HH + ko);
  }
  __syncthreads();

  const int lane = tid & 63;
  const int wave = tid >> 6;
  const int row16 = lane & 15;
  const int quad = lane >> 4;
  const int b = wave * 16 + row16;              // A-fragment row = batch
  const int src = source[b * TT + t];           // source is [B][T]
  const float* arow = emb + (size_t)src * HH + quad * 8;

  f32x4 acc[4];
#pragma unroll
  for (int ct = 0; ct < 4; ++ct) acc[ct] = (f32x4){0.f, 0.f, 0.f, 0.f};

#pragma unroll
  for (int kt = 0; kt < 8; ++kt) {
    const float4 x0 = *(const float4*)(arow + kt * 32);
    const float4 x1 = *(const float4*)(arow + kt * 32 + 4);
    half8_t af;
    af[0] = (_Float16)x0.x; af[1] = (_Float16)x0.y;
    af[2] = (_Float16)x0.z; af[3] = (_Float16)x0.w;
    af[4] = (_Float16)x1.x; af[5] = (_Float16)x1.y;
    af[6] = (_Float16)x1.z; af[7] = (_Float16)x1.w;
#pragma unroll
    for (int ct = 0; ct < 4; ++ct) {
      const half8_t bf = *(const half8_t*)&Bs[ct * 16 + row16][quad * 8 + kt * 32];
      acc[ct] = __builtin_amdgcn_mfma_f32_16x16x32_f16(af, bf, acc[ct], 0, 0, 0);
    }
  }

#pragma unroll
  for (int ct = 0; ct < 4; ++ct) {
    const int nn = nbase + ct * 16 + row16;     // C col = lane&15
    const float bias = b_ih[nn] + b_hh[nn];
#pragma unroll
    for (int r = 0; r < 4; ++r) {
      const int bb = wave * 16 + quad * 4 + r;  // C row = quad*4 + reg
      U[((size_t)t * BB + bb) * HH + nn] = (_Float16)(acc[ct][r] + bias);
    }
  }
}

// ---------------------------------------------------------------------------
// Part B: recurrence via MFMA, weights in AGPRs.
//   R9 post-mortem: "+v" pin put 128 weight regs in ARCH VGPRs (VGPR=132),
//   so ha/uc/addressing shuttled through AGPRs (~205 cy/step VALU). MFMA
//   reads B from AGPR natively -> pin wb with "+a": weights occupy the
//   otherwise-idle AGPR half; arch side keeps the working set (~80 regs).
//   Everything else identical to R9: M-broadcast A-frag (all C rows = y),
//   wave w owns n in [64w,64w+64), 4 tiles x 8 k-chunks = 32 MFMA/step,
//   thread tid finalizes n = tid, 1 barrier/step, 8-step u prefetch chunks.
// ---------------------------------------------------------------------------
__global__ __launch_bounds__(256)
__attribute__((amdgpu_waves_per_eu(1, 1)))
void rnn_scan_kernel(
    const _Float16* __restrict__ U, const _Float16* __restrict__ WhhT,
    float* __restrict__ out) {
  const int b = blockIdx.x;
  const int tid = threadIdx.x;
  const int w = tid >> 6;
  const int l = tid & 63;
  const int col = l & 15;    // n within tile
  const int quad = l >> 4;   // MFMA quad / finalize tile

  __shared__ __align__(16) _Float16 hbuf[2][HH];  // 1 KB ping-pong

  // wb[tt][c]: B-frag for n-tile 64w+16tt, k-chunk c.
  // Lane reads WhhT[(64w+16tt+col)][32c + quad*8 .. +8] (16B aligned).
  half8_t wb[4][8];
#pragma unroll
  for (int tt = 0; tt < 4; ++tt) {
    const _Float16* base = WhhT + (size_t)(64 * w + 16 * tt + col) * HH + quad * 8;
#pragma unroll
    for (int c = 0; c < 8; ++c) wb[tt][c] = *(const half8_t*)(base + 32 * c);
  }
  // Pin into AGPRs ("a" constraint): one-time v_accvgpr_write at setup;
  // MFMA reads B straight from AGPR. Arch VGPRs stay free for ha/uc/addr.
  asm volatile("" : "+a"(wb[0][0]), "+a"(wb[0][1]), "+a"(wb[0][2]), "+a"(wb[0][3]),
                    "+a"(wb[0][4]), "+a"(wb[0][5]), "+a"(wb[0][6]), "+a"(wb[0][7]),
                    "+a"(wb[1][0]), "+a"(wb[1][1]), "+a"(wb[1][2]), "+a"(wb[1][3]),
                    "+a"(wb[1][4]), "+a"(wb[1][5]), "+a"(wb[1][6]), "+a"(wb[1][7]));
  asm volatile("" : "+a"(wb[2][0]), "+a"(wb[2][1]), "+a"(wb[2][2]), "+a"(wb[2][3]),
                    "+a"(wb[2][4]), "+a"(wb[2][5]), "+a"(wb[2][6]), "+a"(wb[2][7]),
                    "+a"(wb[3][0]), "+a"(wb[3][1]), "+a"(wb[3][2]), "+a"(wb[3][3]),
                    "+a"(wb[3][4]), "+a"(wb[3][5]), "+a"(wb[3][6]), "+a"(wb[3][7]));

  hbuf[0][tid] = (_Float16)0.f;  // h0 = 0

  // Thread tid finalizes output n = tid: u stream is per-thread contiguous.
  const _Float16* Up = U + b * HH + tid;  // step stride = BB*HH halfs
  _Float16 uc[8], un[8];
#pragma unroll
  for (int s = 0; s < 8; ++s) uc[s] = Up[(size_t)s * (BB * HH)];

  float hn = 0.f;
  __syncthreads();

  for (int tc = 0; tc < TT; tc += 8) {
    // Issue all next-chunk u-loads; only the first barrier after drains them.
    const int tn = (tc + 8) & (TT - 1);
#pragma unroll
    for (int s = 0; s < 8; ++s) un[s] = Up[(size_t)(tn + s) * (BB * HH)];

#pragma unroll
    for (int s = 0; s < 8; ++s) {
      const int t = tc + s;

      // ---- A-frags: broadcast h chunks; lanes of a quad read same 16B ----
      const _Float16* hrow = hbuf[t & 1] + quad * 8;
      half8_t ha[8];
#pragma unroll
      for (int c = 0; c < 8; ++c) ha[c] = *(const half8_t*)(hrow + 32 * c);
      // Batch: all 8 reads issue first, ONE lgkmcnt wait.
      asm volatile("" : "+v"(ha[0]), "+v"(ha[1]), "+v"(ha[2]), "+v"(ha[3]),
                        "+v"(ha[4]), "+v"(ha[5]), "+v"(ha[6]), "+v"(ha[7]));

      // ---- 32 MFMAs: 4 independent k-chains (one per n-tile) ----
      f32x4 cacc[4];
#pragma unroll
      for (int tt = 0; tt < 4; ++tt) cacc[tt] = (f32x4){0.f, 0.f, 0.f, 0.f};
#pragma unroll
      for (int c = 0; c < 8; ++c)
#pragma unroll
        for (int tt = 0; tt < 4; ++tt)
          cacc[tt] = __builtin_amdgcn_mfma_f32_16x16x32_f16(ha[c], wb[tt][c], cacc[tt], 0, 0, 0);

      // ---- finalize: quad q owns tile q  =>  n = 64w + 16q + col = tid ----
      float y = cacc[0][0];
      y = (quad == 1) ? cacc[1][0] : y;
      y = (quad == 2) ? cacc[2][0] : y;
      y = (quad == 3) ? cacc[3][0] : y;

      const float a = (float)uc[s] + y;
      // tanh(a) = 1 - 2/(exp(2a)+1)
      const float e = __builtin_amdgcn_exp2f(a * 2.885390081777927f);  // 2*log2(e)
      hn = 1.f - 2.f * __builtin_amdgcn_rcpf(e + 1.f);
      hbuf[(t + 1) & 1][tid] = (_Float16)hn;

      __syncthreads();  // single per-step barrier
    }
#pragma unroll
    for (int s = 0; s < 8; ++s) uc[s] = un[s];
  }
  out[(size_t)b * HH + tid] = hn;
}

// ---------------------------------------------------------------------------
extern "C" void kernel_launch(void* const* d_in, const int* in_sizes, int n_in,
                              void* d_out, int out_size, void* d_ws, size_t ws_size,
                              hipStream_t stream) {
  const int*   source = (const int*)d_in[0];
  const float* emb    = (const float*)d_in[1];
  const float* Wih    = (const float*)d_in[2];
  const float* Whh    = (const float*)d_in[3];
  const float* bih    = (const float*)d_in[4];
  const float* bhh    = (const float*)d_in[5];
  float* out = (float*)d_out;

  char* ws = (char*)d_ws;
  _Float16* U    = (_Float16*)ws;                    // 2048*64*256*2 = 67,108,864 B
  _Float16* WihT = (_Float16*)(ws + 67108864);       // 131,072 B
  _Float16* WhhT = (_Float16*)(ws + 67239936);       // 131,072 B (total ~67.4 MB)

  prep_kernel<<<dim3(256), dim3(256), 0, stream>>>(Wih, Whh, WihT, WhhT);
  embed_gemm_kernel<<<dim3(TT, 4), dim3(256), 0, stream>>>(source, emb, WihT, bih, bhh, U);
  rnn_scan_kernel<<<dim3(BB), dim3(256), 0, stream>>>(U, WhhT, out);
}